// Round 18
// baseline (195.129 us; speedup 1.0000x reference)
//
#include <hip/hip_runtime.h>
#include <hip/hip_bf16.h>
#include <cstddef>

#define FD 128   // feature dim D == H == 128

typedef __attribute__((ext_vector_type(8))) short short8v;   // 8 bf16 (4 VGPRs)
typedef __attribute__((ext_vector_type(4))) float f32x4;

__device__ __forceinline__ void atomAddF(float* p, float v) {
    unsafeAtomicAdd(p, v);   // HW global_atomic_add_f32 on gfx950
}

__device__ __forceinline__ unsigned short bf16_rne(float x) {
    unsigned u = __float_as_uint(x);
    return (unsigned short)((u + 0x7fffu + ((u >> 16) & 1u)) >> 16);
}

__device__ __forceinline__ float bf_lo(unsigned u) { return __uint_as_float(u << 16); }
__device__ __forceinline__ float bf_hi(unsigned u) { return __uint_as_float(u & 0xffff0000u); }

// ---- one-time W prep (+ deg zeroing folded in): Wq (fp32 [hop][k][col]) ->
// B-fragment-ordered bf16 (single table; W-lo correction dropped — absmax
// evidence R8..R17 shows error dominated by bf16 q/x rounding; 15.04
// threshold leaves ~4x margin).  Fragment order:
// [hop][kk(4)][ct(8)][lane(64)][j(8)], element =
// W[kk*32 + (lane>>4)*8 + j][ct*16 + (lane&15)].
__global__ void wprep_kern(const float* __restrict__ Wq,
                           unsigned short* __restrict__ whi, int total,
                           int* __restrict__ deg, int N)
{
    int t = blockIdx.x * blockDim.x + threadIdx.x;
    if (t < N) deg[t] = 0;                  // folded memset (hist runs after)
    if (t >= total) return;                 // total = HOPS*2048
    const int hop = t >> 11;
    const int kk  = (t >> 9) & 3;
    const int ct  = (t >> 6) & 7;
    const int l   = t & 63;
    const float* Wh = Wq + (size_t)hop * FD * FD;
    #pragma unroll
    for (int j = 0; j < 8; ++j) {
        float w = Wh[(size_t)(kk * 32 + (l >> 4) * 8 + j) * FD + ct * 16 + (l & 15)];
        whi[(size_t)t * 8 + j] = bf16_rne(w);
    }
}

// ---- q = xin @ Wq[h] + bq[h] via bf16 MFMA.  A = bf16(x), B = bf16(W).
// W fragments LDS-STAGED once per block (32KB); W-reuse: each wave computes
// 32 rows (two 16-row A strips) per B load.  Fused sender-logit
// as_ = q . Wa[:128]  (receiver term cancels in softmax).  q emitted
// bf16-PACKED: q_bfu[row][u] holds cols c0=(u>>4)*32+(u&15) (lo), c0+16 (hi).
// Block: 256 thr = 4 waves; 128 rows/block.
__global__ __launch_bounds__(256) void qkern_mfma(
    const float* __restrict__ xin,
    const unsigned short* __restrict__ whi,
    const float* __restrict__ bq, const float* __restrict__ Wa,
    unsigned* __restrict__ q_bfu, float* __restrict__ as_, int N)
{
    __shared__ unsigned short lds_hi[16384];   // 32KB

    const int t    = threadIdx.x;
    const int lane = t & 63;
    const int w    = t >> 6;                    // wave 0..3
    const int rowBase = blockIdx.x * 128 + w * 32;

    // cooperative stage: 2048 uint4 / 256 thr = 8 trips each
    {
        const uint4* src_hi = (const uint4*)whi;
        uint4* dst_hi = (uint4*)lds_hi;
        #pragma unroll
        for (int i = 0; i < 8; ++i)
            dst_hi[t + i * 256] = src_hi[t + i * 256];
    }
    __syncthreads();
    if (rowBase >= N) return;

    const int kgrp = lane >> 4;                 // 0..3
    const int cidx = lane & 15;

    // A-rows for the two strips (clamped; OOB rows guarded at store)
    int arow0 = rowBase + cidx;       if (arow0 >= N) arow0 = N - 1;
    int arow1 = rowBase + 16 + cidx;  if (arow1 >= N) arow1 = N - 1;
    const float* __restrict__ xr0 = xin + (size_t)arow0 * FD;
    const float* __restrict__ xr1 = xin + (size_t)arow1 * FD;

    f32x4 acc0[8], acc1[8];
    #pragma unroll
    for (int ct = 0; ct < 8; ++ct) {
        acc0[ct] = (f32x4){0.f, 0.f, 0.f, 0.f};
        acc1[ct] = (f32x4){0.f, 0.f, 0.f, 0.f};
    }

    #pragma unroll
    for (int kk = 0; kk < 4; ++kk) {
        const int ko = kk * 32 + kgrp * 8;
        float4 x0a = *(const float4*)(xr0 + ko);
        float4 x0b = *(const float4*)(xr0 + ko + 4);
        float4 x1a = *(const float4*)(xr1 + ko);
        float4 x1b = *(const float4*)(xr1 + ko + 4);
        float v0[8] = {x0a.x, x0a.y, x0a.z, x0a.w, x0b.x, x0b.y, x0b.z, x0b.w};
        float v1[8] = {x1a.x, x1a.y, x1a.z, x1a.w, x1b.x, x1b.y, x1b.z, x1b.w};
        short8v a0, a1;
        #pragma unroll
        for (int j = 0; j < 8; ++j) {
            a0[j] = (short)bf16_rne(v0[j]);
            a1[j] = (short)bf16_rne(v1[j]);
        }
        #pragma unroll
        for (int ct = 0; ct < 8; ++ct) {
            const int fo = ((kk * 8 + ct) * 64 + lane) * 8;
            short8v bhi = *(const short8v*)(lds_hi + fo);
            acc0[ct] = __builtin_amdgcn_mfma_f32_16x16x32_bf16(a0, bhi, acc0[ct], 0, 0, 0);
            acc1[ct] = __builtin_amdgcn_mfma_f32_16x16x32_bf16(a1, bhi, acc1[ct], 0, 0, 0);
        }
    }

    // epilogue: bias, packed-bf16 q store, fused as_ dot — per row strip
    float bqv[8], wav[8];
    #pragma unroll
    for (int ct = 0; ct < 8; ++ct) {
        bqv[ct] = bq[ct * 16 + cidx];
        wav[ct] = Wa[ct * 16 + cidx];
    }
    #pragma unroll
    for (int strip = 0; strip < 2; ++strip) {
        const f32x4* acc = strip ? acc1 : acc0;
        const int sbase = rowBase + strip * 16;
        #pragma unroll
        for (int j = 0; j < 4; ++j) {
            const int row = sbase + kgrp * 4 + j;    // C/D: row=(lane>>4)*4+reg
            const bool ok = row < N;
            float p = 0.f;
            float vv[8];
            #pragma unroll
            for (int ct = 0; ct < 8; ++ct) {
                vv[ct] = acc[ct][j] + bqv[ct];
                p = fmaf(vv[ct], wav[ct], p);
            }
            if (ok) {
                unsigned* qrow = q_bfu + (size_t)row * 64;
                #pragma unroll
                for (int tp = 0; tp < 4; ++tp) {
                    unsigned lo = bf16_rne(vv[2 * tp]);        // col tp*32+cidx
                    unsigned hi = bf16_rne(vv[2 * tp + 1]);    // col tp*32+16+cidx
                    qrow[tp * 16 + cidx] = lo | (hi << 16);
                }
            }
            p += __shfl_xor(p, 1, 64);
            p += __shfl_xor(p, 2, 64);
            p += __shfl_xor(p, 4, 64);
            p += __shfl_xor(p, 8, 64);
            if (ok && cidx == 0) as_[row] = p;
        }
    }
}

// ---------------- CSR build (once; receivers are hop-invariant) -------------
__global__ void hist_kern(const int* __restrict__ rcv, int* __restrict__ deg, int E) {
    int e = blockIdx.x * blockDim.x + threadIdx.x;
    if (e < E) atomicAdd(&deg[rcv[e]], 1);
}

// hierarchical exclusive scan, phase 1: 2048 elems/block, wave-shuffle scan.
__global__ __launch_bounds__(256) void scan1_kern(
    const int* __restrict__ deg, int* __restrict__ rowptr,
    int* __restrict__ bsum, int N)
{
    const int t = threadIdx.x;
    const int base = blockIdx.x * 2048 + t * 8;
    int v[8]; int s = 0;
    #pragma unroll
    for (int j = 0; j < 8; ++j) {
        v[j] = (base + j < N) ? deg[base + j] : 0;
        s += v[j];
    }
    const int lane = t & 63;
    const int wv = t >> 6;   // 0..3
    int incl = s;
    #pragma unroll
    for (int o = 1; o < 64; o <<= 1) {
        int x = __shfl_up(incl, o, 64);
        if (lane >= o) incl += x;
    }
    __shared__ int wsum[4];
    if (lane == 63) wsum[wv] = incl;
    __syncthreads();
    int woff = 0;
    #pragma unroll
    for (int w = 0; w < 4; ++w) woff += (w < wv) ? wsum[w] : 0;
    int excl = woff + incl - s;
    #pragma unroll
    for (int j = 0; j < 8; ++j) {
        if (base + j < N) rowptr[base + j] = excl;
        excl += v[j];
    }
    if (t == 255) bsum[blockIdx.x] = woff + incl;
}

// phase 2: single wave scans block sums (exclusive, in place); writes rowptr[N].
__global__ void scan2_kern(int* __restrict__ bsum, int* __restrict__ rowptr,
                           int nb, int N, int E)
{
    const int lane = threadIdx.x;   // 64 threads
    int carry = 0;
    for (int c = 0; c < nb; c += 64) {
        int i = c + lane;
        int v = (i < nb) ? bsum[i] : 0;
        int incl = v;
        #pragma unroll
        for (int o = 1; o < 64; o <<= 1) {
            int x = __shfl_up(incl, o, 64);
            if (lane >= o) incl += x;
        }
        if (i < nb) bsum[i] = carry + incl - v;
        carry += __shfl(incl, 63, 64);
    }
    if (lane == 0) rowptr[N] = E;
}

// phase 3: add block offsets; fill cursor copy; zero agg (folded memset).
__global__ void scan3_kern(int* __restrict__ rowptr, int* __restrict__ cursor,
                           const int* __restrict__ bsum, int N,
                           float* __restrict__ agg, int aggN)
{
    int i = blockIdx.x * blockDim.x + threadIdx.x;
    if (i < aggN) agg[i] = 0.f;     // agg only written much later (agg_kern)
    if (i >= N) return;
    int v = rowptr[i] + bsum[i >> 11];
    rowptr[i] = v;
    cursor[i] = v;
}

__global__ void fill_kern(const int* __restrict__ snd, const int* __restrict__ rcv,
                          int* __restrict__ cursor, int* __restrict__ csr_snd, int E)
{
    int e = blockIdx.x * blockDim.x + threadIdx.x;
    if (e >= E) return;
    int pos = atomicAdd(&cursor[rcv[e]], 1);
    csr_snd[pos] = snd[e];
}

// ---------------- fused pull-based GAT node update --------------------------
// TWO nodes per wave (one per 32-lane half; 8 nodes / 256-block).  Softmax
// over as_[senders] (receiver terms cancel), no max-shift in the common path
// (logits are O(5); exp cannot overflow).  deg<=32 path: csr/as_ gathered
// once into the half's registers, 5-level in-half reduce.  Feature loop:
// 16 EDGES per trip per node — each lane issues EIGHT independent uint4
// loads (slots es, es+2, ..., es+14) so ~98% of nodes (deg<=16) finish the
// whole gather in ONE round with 8 loads in flight (R15/R16/R17 lesson:
// gather MLP depth is the only remaining lever).  1-level combine; float4
// stores.  Per-half 32-lane fallback for deg>32.
__global__ __launch_bounds__(256) void gat_node_kern(
    const unsigned* __restrict__ q_bfu, const float* __restrict__ as_,
    const int* __restrict__ rowptr, const int* __restrict__ csr_snd,
    float* __restrict__ xout, int N)
{
    const int lane = threadIdx.x & 63;
    const int l32  = lane & 31;
    const int base32 = lane & 32;          // 0 or 32 (half base)
    const int n = blockIdx.x * 8 + (threadIdx.x >> 5);
    if (n >= N) return;
    const int start = rowptr[n], end = rowptr[n + 1];
    const int deg = end - start;

    if (deg <= 32) {
        const int i = start + l32;
        const bool valid = i < end;
        const int   s_c = valid ? csr_snd[i] : 0;
        const float e = valid ? __expf(as_[s_c]) : 0.f;
        float d = e;
        #pragma unroll
        for (int o = 1; o < 32; o <<= 1) d += __shfl_xor(d, o, 64);   // in-half
        const float wgt = e * ((d > 0.f) ? (1.f / d) : 0.f);

        const int es = l32 >> 4;       // edge slot within half: 0..1
        const int ql = lane & 15;      // lane within edge group
        float4 accLo = make_float4(0.f, 0.f, 0.f, 0.f);
        float4 accHi = make_float4(0.f, 0.f, 0.f, 0.f);
        for (int kb = 0; kb < deg; kb += 16) {
            int   sv[8];
            float cv[8];
            #pragma unroll
            for (int u = 0; u < 8; ++u) {
                const int k = kb + es + 2 * u;
                const int idx = (k < deg) ? k : (deg - 1);
                sv[u] = __shfl(s_c, base32 + idx, 64);
                cv[u] = __shfl(wgt, base32 + idx, 64);
                if (k >= deg) cv[u] = 0.f;
            }
            uint4 pv[8];
            #pragma unroll
            for (int u = 0; u < 8; ++u)
                pv[u] = *(const uint4*)(q_bfu + (size_t)sv[u] * 64 + 4 * ql);
            #pragma unroll
            for (int u = 0; u < 8; ++u) {
                const float c = cv[u];
                accLo.x = fmaf(c, bf_lo(pv[u].x), accLo.x);
                accHi.x = fmaf(c, bf_hi(pv[u].x), accHi.x);
                accLo.y = fmaf(c, bf_lo(pv[u].y), accLo.y);
                accHi.y = fmaf(c, bf_hi(pv[u].y), accHi.y);
                accLo.z = fmaf(c, bf_lo(pv[u].z), accLo.z);
                accHi.z = fmaf(c, bf_hi(pv[u].z), accHi.z);
                accLo.w = fmaf(c, bf_lo(pv[u].w), accLo.w);
                accHi.w = fmaf(c, bf_hi(pv[u].w), accHi.w);
            }
        }
        // combine the 2 edge slots (xor 16 — stays within the half)
        accLo.x += __shfl_xor(accLo.x, 16, 64);
        accLo.y += __shfl_xor(accLo.y, 16, 64);
        accLo.z += __shfl_xor(accLo.z, 16, 64);
        accLo.w += __shfl_xor(accLo.w, 16, 64);
        accHi.x += __shfl_xor(accHi.x, 16, 64);
        accHi.y += __shfl_xor(accHi.y, 16, 64);
        accHi.z += __shfl_xor(accHi.z, 16, 64);
        accHi.w += __shfl_xor(accHi.w, 16, 64);
        if (es == 0) {
            // lane ql holds uints u=4*ql..4*ql+3: lo -> cols c0..c0+3, hi -> +16
            const int c0 = (ql >> 2) * 32 + (ql & 3) * 4;
            float4 lo4, hi4;
            lo4.x = accLo.x > 0.f ? accLo.x : 0.01f * accLo.x;
            lo4.y = accLo.y > 0.f ? accLo.y : 0.01f * accLo.y;
            lo4.z = accLo.z > 0.f ? accLo.z : 0.01f * accLo.z;
            lo4.w = accLo.w > 0.f ? accLo.w : 0.01f * accLo.w;
            hi4.x = accHi.x > 0.f ? accHi.x : 0.01f * accHi.x;
            hi4.y = accHi.y > 0.f ? accHi.y : 0.01f * accHi.y;
            hi4.z = accHi.z > 0.f ? accHi.z : 0.01f * accHi.z;
            hi4.w = accHi.w > 0.f ? accHi.w : 0.01f * accHi.w;
            *(float4*)(xout + (size_t)n * FD + c0)      = lo4;
            *(float4*)(xout + (size_t)n * FD + c0 + 16) = hi4;
        }
    } else {
        // generic per-half fallback (rare): 3-pass with max-shift, 32 lanes
        float m = -3.4e38f;
        for (int i = start + l32; i < end; i += 32) m = fmaxf(m, as_[csr_snd[i]]);
        #pragma unroll
        for (int o = 1; o < 32; o <<= 1) m = fmaxf(m, __shfl_xor(m, o, 64));
        float d = 0.f;
        for (int i = start + l32; i < end; i += 32) d += __expf(as_[csr_snd[i]] - m);
        #pragma unroll
        for (int o = 1; o < 32; o <<= 1) d += __shfl_xor(d, o, 64);
        const float inv = (d > 0.f) ? (1.f / d) : 0.f;
        float ax0 = 0.f, ay0 = 0.f, ax1 = 0.f, ay1 = 0.f;
        for (int i = start; i < end; ++i) {
            const int s = csr_snd[i];
            const float coef = __expf(as_[s] - m) * inv;
            const uint2 pv = *(const uint2*)(q_bfu + (size_t)s * 64 + 2 * l32);
            ax0 = fmaf(coef, bf_lo(pv.x), ax0);
            ay0 = fmaf(coef, bf_hi(pv.x), ay0);
            ax1 = fmaf(coef, bf_lo(pv.y), ax1);
            ay1 = fmaf(coef, bf_hi(pv.y), ay1);
        }
        ax0 = ax0 > 0.f ? ax0 : 0.01f * ax0;
        ay0 = ay0 > 0.f ? ay0 : 0.01f * ay0;
        ax1 = ax1 > 0.f ? ax1 : 0.01f * ax1;
        ay1 = ay1 > 0.f ? ay1 : 0.01f * ay1;
        const int u0 = 2 * l32, u1 = u0 + 1;
        const int c00 = (u0 >> 4) * 32 + (u0 & 15);
        const int c10 = (u1 >> 4) * 32 + (u1 & 15);
        xout[(size_t)n * FD + c00]      = ax0;
        xout[(size_t)n * FD + c00 + 16] = ay0;
        xout[(size_t)n * FD + c10]      = ax1;
        xout[(size_t)n * FD + c10 + 16] = ay1;
    }
}

// agg[g] = sum of x rows with gidx==g (gidx sorted -> run-length accumulate)
__global__ __launch_bounds__(256) void agg_kern(
    const float* __restrict__ x, const int* __restrict__ gidx,
    float* __restrict__ agg, int N)
{
    const int c  = threadIdx.x & 127;
    const int rl = threadIdx.x >> 7;   // 0..1
    int n   = blockIdx.x * 128 + rl;
    int end = blockIdx.x * 128 + 128;
    if (end > N) end = N;
    float acc = 0.f; int curg = -1;
    for (; n < end; n += 2) {
        int g = gidx[n];
        if (g != curg) {
            if (curg >= 0) atomAddF(&agg[(size_t)curg * FD + c], acc);
            curg = g; acc = 0.f;
        }
        acc += x[(size_t)n * FD + c];
    }
    if (curg >= 0) atomAddF(&agg[(size_t)curg * FD + c], acc);
}

// g_out = concat([agg, globals]) @ Wg + bg.  One block per graph; 256 thr =
// 2 split-K halves x 128 output cols; Wg reads coalesced across cols.
__global__ __launch_bounds__(256) void glob_kern(
    const float* __restrict__ agg, const float* __restrict__ glb,
    const float* __restrict__ Wg, const float* __restrict__ bg,
    float* __restrict__ gout, int G)
{
    __shared__ float xv[256];
    __shared__ float part[128];
    const int g = blockIdx.x;
    const int t = threadIdx.x;
    if (t < 128) xv[t] = agg[(size_t)g * FD + t];
    else         xv[t] = glb[(size_t)g * FD + (t - 128)];
    __syncthreads();
    const int c = t & 127, half = t >> 7;
    const float* __restrict__ W = Wg + (size_t)half * FD * FD;
    const float* __restrict__ xh = xv + half * FD;
    float acc = 0.f;
    #pragma unroll 8
    for (int k = 0; k < FD; ++k)
        acc = fmaf(xh[k], W[(size_t)k * FD + c], acc);
    if (half == 1) part[c] = acc;
    __syncthreads();
    if (half == 0) gout[(size_t)g * FD + c] = acc + part[c] + bg[c];
}

extern "C" void kernel_launch(void* const* d_in, const int* in_sizes, int n_in,
                              void* d_out, int out_size, void* d_ws, size_t ws_size,
                              hipStream_t stream)
{
    const float* nodes    = (const float*)d_in[0];
    const float* globals_ = (const float*)d_in[1];
    const float* Wq       = (const float*)d_in[2];
    const float* bq       = (const float*)d_in[3];
    const float* Wa       = (const float*)d_in[4];
    const float* ba       = (const float*)d_in[5];  (void)ba;  // cancels in softmax
    const float* Wg       = (const float*)d_in[6];
    const float* bg       = (const float*)d_in[7];
    const int* senders    = (const int*)d_in[8];
    const int* receivers  = (const int*)d_in[9];
    const int* gidx       = (const int*)d_in[10];

    const int N    = in_sizes[0] / FD;
    const int G    = in_sizes[1] / FD;
    const int E    = in_sizes[8];
    const int HOPS = in_sizes[3] / FD;
    const int NB   = (N + 2047) / 2048;   // scan blocks

    // workspace layout
    float* ws = (float*)d_ws;
    size_t off = 0;
    unsigned* q_bfu = (unsigned*)ws;  off += (size_t)N * 64;   // packed bf16 q
    float* xbuf = ws + off;        off += (size_t)N * FD;
    float* agg  = ws + off;        off += (size_t)G * FD;
    float* as_  = ws + off;        off += N;
    int* deg     = (int*)(ws + off); off += N;
    int* rowptr  = (int*)(ws + off); off += N + 1;
    int* cursor  = (int*)(ws + off); off += N;
    int* bsum    = (int*)(ws + off); off += NB;
    int* csr_snd = (int*)(ws + off); off += E;
    off = (off + 3) & ~(size_t)3;                       // 16B-align for short8 loads
    unsigned short* wq_hi = (unsigned short*)(ws + off); off += (size_t)HOPS * 16384 / 2;

    float* xout_final = (float*)d_out;                  // N*FD
    float* gout = (float*)d_out + (size_t)N * FD;       // G*FD

    // ---- one-time prep: W frags + deg zero (fused), CSR, agg zero (fused)
    const int wtot = HOPS * 2048;
    const int wgrid = (((N > wtot) ? N : wtot) + 255) / 256;
    wprep_kern<<<wgrid, 256, 0, stream>>>(Wq, wq_hi, wtot, deg, N);
    hist_kern<<<(E + 255) / 256, 256, 0, stream>>>(receivers, deg, E);
    scan1_kern<<<NB, 256, 0, stream>>>(deg, rowptr, bsum, N);
    scan2_kern<<<1, 64, 0, stream>>>(bsum, rowptr, NB, N, E);
    scan3_kern<<<(N + 255) / 256, 256, 0, stream>>>(rowptr, cursor, bsum, N,
                                                    agg, G * FD);
    fill_kern<<<(E + 255) / 256, 256, 0, stream>>>(senders, receivers, cursor, csr_snd, E);

    const float* xin = nodes;
    for (int h = 0; h < HOPS; ++h) {
        float* xout = (h == HOPS - 1) ? xout_final : xbuf;
        const unsigned short* whi_h = wq_hi + (size_t)h * 16384;
        const float* bq_h = bq + (size_t)h * FD;
        const float* Wa_h = Wa + (size_t)h * 2 * FD;

        qkern_mfma<<<(N + 127) / 128, 256, 0, stream>>>(xin, whi_h, bq_h,
                                                        Wa_h, q_bfu, as_, N);
        gat_node_kern<<<(N + 7) / 8, 256, 0, stream>>>(q_bfu, as_, rowptr, csr_snd,
                                                       xout, N);
        xin = xout;
    }

    agg_kern<<<(N + 127) / 128, 256, 0, stream>>>(xin, gidx, agg, N);
    glob_kern<<<G, 256, 0, stream>>>(agg, globals_, Wg, bg, gout, G);
}

// Round 19
// 185.744 us; speedup vs baseline: 1.0505x; 1.0505x over previous
//
#include <hip/hip_runtime.h>
#include <hip/hip_bf16.h>
#include <cstddef>

#define FD 128   // feature dim D == H == 128

typedef __attribute__((ext_vector_type(8))) short short8v;   // 8 bf16 (4 VGPRs)
typedef __attribute__((ext_vector_type(4))) float f32x4;

__device__ __forceinline__ void atomAddF(float* p, float v) {
    unsafeAtomicAdd(p, v);   // HW global_atomic_add_f32 on gfx950
}

__device__ __forceinline__ unsigned short bf16_rne(float x) {
    unsigned u = __float_as_uint(x);
    return (unsigned short)((u + 0x7fffu + ((u >> 16) & 1u)) >> 16);
}

__device__ __forceinline__ float bf_lo(unsigned u) { return __uint_as_float(u << 16); }
__device__ __forceinline__ float bf_hi(unsigned u) { return __uint_as_float(u & 0xffff0000u); }

// ---- one-time W prep (+ deg zeroing folded in): Wq (fp32 [hop][k][col]) ->
// B-fragment-ordered bf16 (single table; W-lo correction dropped — absmax
// evidence R8..R17 shows error dominated by bf16 q/x rounding; 15.04
// threshold leaves ~4x margin).  Fragment order:
// [hop][kk(4)][ct(8)][lane(64)][j(8)], element =
// W[kk*32 + (lane>>4)*8 + j][ct*16 + (lane&15)].
__global__ void wprep_kern(const float* __restrict__ Wq,
                           unsigned short* __restrict__ whi, int total,
                           int* __restrict__ deg, int N)
{
    int t = blockIdx.x * blockDim.x + threadIdx.x;
    if (t < N) deg[t] = 0;                  // folded memset (hist runs after)
    if (t >= total) return;                 // total = HOPS*2048
    const int hop = t >> 11;
    const int kk  = (t >> 9) & 3;
    const int ct  = (t >> 6) & 7;
    const int l   = t & 63;
    const float* Wh = Wq + (size_t)hop * FD * FD;
    #pragma unroll
    for (int j = 0; j < 8; ++j) {
        float w = Wh[(size_t)(kk * 32 + (l >> 4) * 8 + j) * FD + ct * 16 + (l & 15)];
        whi[(size_t)t * 8 + j] = bf16_rne(w);
    }
}

// ---- q = xin @ Wq[h] + bq[h] via bf16 MFMA.  A = bf16(x), B = bf16(W)
// (single table).  W fragments LDS-STAGED once per block (32KB); W-reuse:
// each wave computes 32 rows (two 16-row A strips) per B load.  Fused
// sender-logit as_ = q . Wa[:128]  (receiver term cancels in softmax).
// q emitted bf16-PACKED: q_bfu[row][u] holds cols c0=(u>>4)*32+(u&15) (lo),
// c0+16 (hi).  Block: 256 thr = 4 waves; 128 rows/block.
__global__ __launch_bounds__(256) void qkern_mfma(
    const float* __restrict__ xin,
    const unsigned short* __restrict__ whi,
    const float* __restrict__ bq, const float* __restrict__ Wa,
    unsigned* __restrict__ q_bfu, float* __restrict__ as_, int N)
{
    __shared__ unsigned short lds_hi[16384];   // 32KB

    const int t    = threadIdx.x;
    const int lane = t & 63;
    const int w    = t >> 6;                    // wave 0..3
    const int rowBase = blockIdx.x * 128 + w * 32;

    // cooperative stage: 2048 uint4 / 256 thr = 8 trips each
    {
        const uint4* src_hi = (const uint4*)whi;
        uint4* dst_hi = (uint4*)lds_hi;
        #pragma unroll
        for (int i = 0; i < 8; ++i)
            dst_hi[t + i * 256] = src_hi[t + i * 256];
    }
    __syncthreads();
    if (rowBase >= N) return;

    const int kgrp = lane >> 4;                 // 0..3
    const int cidx = lane & 15;

    // A-rows for the two strips (clamped; OOB rows guarded at store)
    int arow0 = rowBase + cidx;       if (arow0 >= N) arow0 = N - 1;
    int arow1 = rowBase + 16 + cidx;  if (arow1 >= N) arow1 = N - 1;
    const float* __restrict__ xr0 = xin + (size_t)arow0 * FD;
    const float* __restrict__ xr1 = xin + (size_t)arow1 * FD;

    f32x4 acc0[8], acc1[8];
    #pragma unroll
    for (int ct = 0; ct < 8; ++ct) {
        acc0[ct] = (f32x4){0.f, 0.f, 0.f, 0.f};
        acc1[ct] = (f32x4){0.f, 0.f, 0.f, 0.f};
    }

    #pragma unroll
    for (int kk = 0; kk < 4; ++kk) {
        const int ko = kk * 32 + kgrp * 8;
        float4 x0a = *(const float4*)(xr0 + ko);
        float4 x0b = *(const float4*)(xr0 + ko + 4);
        float4 x1a = *(const float4*)(xr1 + ko);
        float4 x1b = *(const float4*)(xr1 + ko + 4);
        float v0[8] = {x0a.x, x0a.y, x0a.z, x0a.w, x0b.x, x0b.y, x0b.z, x0b.w};
        float v1[8] = {x1a.x, x1a.y, x1a.z, x1a.w, x1b.x, x1b.y, x1b.z, x1b.w};
        short8v a0, a1;
        #pragma unroll
        for (int j = 0; j < 8; ++j) {
            a0[j] = (short)bf16_rne(v0[j]);
            a1[j] = (short)bf16_rne(v1[j]);
        }
        #pragma unroll
        for (int ct = 0; ct < 8; ++ct) {
            const int fo = ((kk * 8 + ct) * 64 + lane) * 8;
            short8v bhi = *(const short8v*)(lds_hi + fo);
            acc0[ct] = __builtin_amdgcn_mfma_f32_16x16x32_bf16(a0, bhi, acc0[ct], 0, 0, 0);
            acc1[ct] = __builtin_amdgcn_mfma_f32_16x16x32_bf16(a1, bhi, acc1[ct], 0, 0, 0);
        }
    }

    // epilogue: bias, packed-bf16 q store, fused as_ dot — per row strip
    float bqv[8], wav[8];
    #pragma unroll
    for (int ct = 0; ct < 8; ++ct) {
        bqv[ct] = bq[ct * 16 + cidx];
        wav[ct] = Wa[ct * 16 + cidx];
    }
    #pragma unroll
    for (int strip = 0; strip < 2; ++strip) {
        const f32x4* acc = strip ? acc1 : acc0;
        const int sbase = rowBase + strip * 16;
        #pragma unroll
        for (int j = 0; j < 4; ++j) {
            const int row = sbase + kgrp * 4 + j;    // C/D: row=(lane>>4)*4+reg
            const bool ok = row < N;
            float p = 0.f;
            float vv[8];
            #pragma unroll
            for (int ct = 0; ct < 8; ++ct) {
                vv[ct] = acc[ct][j] + bqv[ct];
                p = fmaf(vv[ct], wav[ct], p);
            }
            if (ok) {
                unsigned* qrow = q_bfu + (size_t)row * 64;
                #pragma unroll
                for (int tp = 0; tp < 4; ++tp) {
                    unsigned lo = bf16_rne(vv[2 * tp]);        // col tp*32+cidx
                    unsigned hi = bf16_rne(vv[2 * tp + 1]);    // col tp*32+16+cidx
                    qrow[tp * 16 + cidx] = lo | (hi << 16);
                }
            }
            p += __shfl_xor(p, 1, 64);
            p += __shfl_xor(p, 2, 64);
            p += __shfl_xor(p, 4, 64);
            p += __shfl_xor(p, 8, 64);
            if (ok && cidx == 0) as_[row] = p;
        }
    }
}

// ---------------- CSR build (once; receivers are hop-invariant) -------------
__global__ void hist_kern(const int* __restrict__ rcv, int* __restrict__ deg, int E) {
    int e = blockIdx.x * blockDim.x + threadIdx.x;
    if (e < E) atomicAdd(&deg[rcv[e]], 1);
}

// hierarchical exclusive scan, phase 1: 2048 elems/block, wave-shuffle scan.
__global__ __launch_bounds__(256) void scan1_kern(
    const int* __restrict__ deg, int* __restrict__ rowptr,
    int* __restrict__ bsum, int N)
{
    const int t = threadIdx.x;
    const int base = blockIdx.x * 2048 + t * 8;
    int v[8]; int s = 0;
    #pragma unroll
    for (int j = 0; j < 8; ++j) {
        v[j] = (base + j < N) ? deg[base + j] : 0;
        s += v[j];
    }
    const int lane = t & 63;
    const int wv = t >> 6;   // 0..3
    int incl = s;
    #pragma unroll
    for (int o = 1; o < 64; o <<= 1) {
        int x = __shfl_up(incl, o, 64);
        if (lane >= o) incl += x;
    }
    __shared__ int wsum[4];
    if (lane == 63) wsum[wv] = incl;
    __syncthreads();
    int woff = 0;
    #pragma unroll
    for (int w = 0; w < 4; ++w) woff += (w < wv) ? wsum[w] : 0;
    int excl = woff + incl - s;
    #pragma unroll
    for (int j = 0; j < 8; ++j) {
        if (base + j < N) rowptr[base + j] = excl;
        excl += v[j];
    }
    if (t == 255) bsum[blockIdx.x] = woff + incl;
}

// phase 2: single wave scans block sums (exclusive, in place); writes rowptr[N].
__global__ void scan2_kern(int* __restrict__ bsum, int* __restrict__ rowptr,
                           int nb, int N, int E)
{
    const int lane = threadIdx.x;   // 64 threads
    int carry = 0;
    for (int c = 0; c < nb; c += 64) {
        int i = c + lane;
        int v = (i < nb) ? bsum[i] : 0;
        int incl = v;
        #pragma unroll
        for (int o = 1; o < 64; o <<= 1) {
            int x = __shfl_up(incl, o, 64);
            if (lane >= o) incl += x;
        }
        if (i < nb) bsum[i] = carry + incl - v;
        carry += __shfl(incl, 63, 64);
    }
    if (lane == 0) rowptr[N] = E;
}

// phase 3: add block offsets; fill cursor copy; zero agg (folded memset).
__global__ void scan3_kern(int* __restrict__ rowptr, int* __restrict__ cursor,
                           const int* __restrict__ bsum, int N,
                           float* __restrict__ agg, int aggN)
{
    int i = blockIdx.x * blockDim.x + threadIdx.x;
    if (i < aggN) agg[i] = 0.f;     // agg only written much later (agg_kern)
    if (i >= N) return;
    int v = rowptr[i] + bsum[i >> 11];
    rowptr[i] = v;
    cursor[i] = v;
}

__global__ void fill_kern(const int* __restrict__ snd, const int* __restrict__ rcv,
                          int* __restrict__ cursor, int* __restrict__ csr_snd, int E)
{
    int e = blockIdx.x * blockDim.x + threadIdx.x;
    if (e >= E) return;
    int pos = atomicAdd(&cursor[rcv[e]], 1);
    csr_snd[pos] = snd[e];
}

// ---------------- fused pull-based GAT node update --------------------------
// TWO nodes per wave (one per 32-lane half; 8 nodes / 256-block).  Softmax
// over as_[senders] (receiver terms cancel), no max-shift in the common path
// (logits are O(5); exp cannot overflow).  deg<=32 path: csr/as_ gathered
// once into the half's registers, 5-level in-half reduce.  Feature loop:
// 8 EDGES per trip per node — each lane issues FOUR independent uint4 loads
// (slots es, es+2, es+4, es+6): the measured optimum (R16); depth 8/lane
// (R18) regressed on redundant clamped loads.  1-level combine; float4
// stores.  Per-half 32-lane fallback for deg>32.
__global__ __launch_bounds__(256) void gat_node_kern(
    const unsigned* __restrict__ q_bfu, const float* __restrict__ as_,
    const int* __restrict__ rowptr, const int* __restrict__ csr_snd,
    float* __restrict__ xout, int N)
{
    const int lane = threadIdx.x & 63;
    const int l32  = lane & 31;
    const int base32 = lane & 32;          // 0 or 32 (half base)
    const int n = blockIdx.x * 8 + (threadIdx.x >> 5);
    if (n >= N) return;
    const int start = rowptr[n], end = rowptr[n + 1];
    const int deg = end - start;

    if (deg <= 32) {
        const int i = start + l32;
        const bool valid = i < end;
        const int   s_c = valid ? csr_snd[i] : 0;
        const float e = valid ? __expf(as_[s_c]) : 0.f;
        float d = e;
        #pragma unroll
        for (int o = 1; o < 32; o <<= 1) d += __shfl_xor(d, o, 64);   // in-half
        const float wgt = e * ((d > 0.f) ? (1.f / d) : 0.f);

        const int es = l32 >> 4;       // edge slot within half: 0..1
        const int ql = lane & 15;      // lane within edge group
        float4 accLo = make_float4(0.f, 0.f, 0.f, 0.f);
        float4 accHi = make_float4(0.f, 0.f, 0.f, 0.f);
        for (int kb = 0; kb < deg; kb += 8) {
            int   sv[4];
            float cv[4];
            #pragma unroll
            for (int u = 0; u < 4; ++u) {
                const int k = kb + es + 2 * u;
                const int idx = (k < deg) ? k : (deg - 1);
                sv[u] = __shfl(s_c, base32 + idx, 64);
                cv[u] = __shfl(wgt, base32 + idx, 64);
                if (k >= deg) cv[u] = 0.f;
            }
            uint4 pv[4];
            #pragma unroll
            for (int u = 0; u < 4; ++u)
                pv[u] = *(const uint4*)(q_bfu + (size_t)sv[u] * 64 + 4 * ql);
            #pragma unroll
            for (int u = 0; u < 4; ++u) {
                const float c = cv[u];
                accLo.x = fmaf(c, bf_lo(pv[u].x), accLo.x);
                accHi.x = fmaf(c, bf_hi(pv[u].x), accHi.x);
                accLo.y = fmaf(c, bf_lo(pv[u].y), accLo.y);
                accHi.y = fmaf(c, bf_hi(pv[u].y), accHi.y);
                accLo.z = fmaf(c, bf_lo(pv[u].z), accLo.z);
                accHi.z = fmaf(c, bf_hi(pv[u].z), accHi.z);
                accLo.w = fmaf(c, bf_lo(pv[u].w), accLo.w);
                accHi.w = fmaf(c, bf_hi(pv[u].w), accHi.w);
            }
        }
        // combine the 2 edge slots (xor 16 — stays within the half)
        accLo.x += __shfl_xor(accLo.x, 16, 64);
        accLo.y += __shfl_xor(accLo.y, 16, 64);
        accLo.z += __shfl_xor(accLo.z, 16, 64);
        accLo.w += __shfl_xor(accLo.w, 16, 64);
        accHi.x += __shfl_xor(accHi.x, 16, 64);
        accHi.y += __shfl_xor(accHi.y, 16, 64);
        accHi.z += __shfl_xor(accHi.z, 16, 64);
        accHi.w += __shfl_xor(accHi.w, 16, 64);
        if (es == 0) {
            // lane ql holds uints u=4*ql..4*ql+3: lo -> cols c0..c0+3, hi -> +16
            const int c0 = (ql >> 2) * 32 + (ql & 3) * 4;
            float4 lo4, hi4;
            lo4.x = accLo.x > 0.f ? accLo.x : 0.01f * accLo.x;
            lo4.y = accLo.y > 0.f ? accLo.y : 0.01f * accLo.y;
            lo4.z = accLo.z > 0.f ? accLo.z : 0.01f * accLo.z;
            lo4.w = accLo.w > 0.f ? accLo.w : 0.01f * accLo.w;
            hi4.x = accHi.x > 0.f ? accHi.x : 0.01f * accHi.x;
            hi4.y = accHi.y > 0.f ? accHi.y : 0.01f * accHi.y;
            hi4.z = accHi.z > 0.f ? accHi.z : 0.01f * accHi.z;
            hi4.w = accHi.w > 0.f ? accHi.w : 0.01f * accHi.w;
            *(float4*)(xout + (size_t)n * FD + c0)      = lo4;
            *(float4*)(xout + (size_t)n * FD + c0 + 16) = hi4;
        }
    } else {
        // generic per-half fallback (rare): 3-pass with max-shift, 32 lanes
        float m = -3.4e38f;
        for (int i = start + l32; i < end; i += 32) m = fmaxf(m, as_[csr_snd[i]]);
        #pragma unroll
        for (int o = 1; o < 32; o <<= 1) m = fmaxf(m, __shfl_xor(m, o, 64));
        float d = 0.f;
        for (int i = start + l32; i < end; i += 32) d += __expf(as_[csr_snd[i]] - m);
        #pragma unroll
        for (int o = 1; o < 32; o <<= 1) d += __shfl_xor(d, o, 64);
        const float inv = (d > 0.f) ? (1.f / d) : 0.f;
        float ax0 = 0.f, ay0 = 0.f, ax1 = 0.f, ay1 = 0.f;
        for (int i = start; i < end; ++i) {
            const int s = csr_snd[i];
            const float coef = __expf(as_[s] - m) * inv;
            const uint2 pv = *(const uint2*)(q_bfu + (size_t)s * 64 + 2 * l32);
            ax0 = fmaf(coef, bf_lo(pv.x), ax0);
            ay0 = fmaf(coef, bf_hi(pv.x), ay0);
            ax1 = fmaf(coef, bf_lo(pv.y), ax1);
            ay1 = fmaf(coef, bf_hi(pv.y), ay1);
        }
        ax0 = ax0 > 0.f ? ax0 : 0.01f * ax0;
        ay0 = ay0 > 0.f ? ay0 : 0.01f * ay0;
        ax1 = ax1 > 0.f ? ax1 : 0.01f * ax1;
        ay1 = ay1 > 0.f ? ay1 : 0.01f * ay1;
        const int u0 = 2 * l32, u1 = u0 + 1;
        const int c00 = (u0 >> 4) * 32 + (u0 & 15);
        const int c10 = (u1 >> 4) * 32 + (u1 & 15);
        xout[(size_t)n * FD + c00]      = ax0;
        xout[(size_t)n * FD + c00 + 16] = ay0;
        xout[(size_t)n * FD + c10]      = ax1;
        xout[(size_t)n * FD + c10 + 16] = ay1;
    }
}

// agg[g] = sum of x rows with gidx==g (gidx sorted -> run-length accumulate)
__global__ __launch_bounds__(256) void agg_kern(
    const float* __restrict__ x, const int* __restrict__ gidx,
    float* __restrict__ agg, int N)
{
    const int c  = threadIdx.x & 127;
    const int rl = threadIdx.x >> 7;   // 0..1
    int n   = blockIdx.x * 128 + rl;
    int end = blockIdx.x * 128 + 128;
    if (end > N) end = N;
    float acc = 0.f; int curg = -1;
    for (; n < end; n += 2) {
        int g = gidx[n];
        if (g != curg) {
            if (curg >= 0) atomAddF(&agg[(size_t)curg * FD + c], acc);
            curg = g; acc = 0.f;
        }
        acc += x[(size_t)n * FD + c];
    }
    if (curg >= 0) atomAddF(&agg[(size_t)curg * FD + c], acc);
}

// g_out = concat([agg, globals]) @ Wg + bg.  One block per graph; 256 thr =
// 2 split-K halves x 128 output cols; Wg reads coalesced across cols.
__global__ __launch_bounds__(256) void glob_kern(
    const float* __restrict__ agg, const float* __restrict__ glb,
    const float* __restrict__ Wg, const float* __restrict__ bg,
    float* __restrict__ gout, int G)
{
    __shared__ float xv[256];
    __shared__ float part[128];
    const int g = blockIdx.x;
    const int t = threadIdx.x;
    if (t < 128) xv[t] = agg[(size_t)g * FD + t];
    else         xv[t] = glb[(size_t)g * FD + (t - 128)];
    __syncthreads();
    const int c = t & 127, half = t >> 7;
    const float* __restrict__ W = Wg + (size_t)half * FD * FD;
    const float* __restrict__ xh = xv + half * FD;
    float acc = 0.f;
    #pragma unroll 8
    for (int k = 0; k < FD; ++k)
        acc = fmaf(xh[k], W[(size_t)k * FD + c], acc);
    if (half == 1) part[c] = acc;
    __syncthreads();
    if (half == 0) gout[(size_t)g * FD + c] = acc + part[c] + bg[c];
}

extern "C" void kernel_launch(void* const* d_in, const int* in_sizes, int n_in,
                              void* d_out, int out_size, void* d_ws, size_t ws_size,
                              hipStream_t stream)
{
    const float* nodes    = (const float*)d_in[0];
    const float* globals_ = (const float*)d_in[1];
    const float* Wq       = (const float*)d_in[2];
    const float* bq       = (const float*)d_in[3];
    const float* Wa       = (const float*)d_in[4];
    const float* ba       = (const float*)d_in[5];  (void)ba;  // cancels in softmax
    const float* Wg       = (const float*)d_in[6];
    const float* bg       = (const float*)d_in[7];
    const int* senders    = (const int*)d_in[8];
    const int* receivers  = (const int*)d_in[9];
    const int* gidx       = (const int*)d_in[10];

    const int N    = in_sizes[0] / FD;
    const int G    = in_sizes[1] / FD;
    const int E    = in_sizes[8];
    const int HOPS = in_sizes[3] / FD;
    const int NB   = (N + 2047) / 2048;   // scan blocks

    // workspace layout
    float* ws = (float*)d_ws;
    size_t off = 0;
    unsigned* q_bfu = (unsigned*)ws;  off += (size_t)N * 64;   // packed bf16 q
    float* xbuf = ws + off;        off += (size_t)N * FD;
    float* agg  = ws + off;        off += (size_t)G * FD;
    float* as_  = ws + off;        off += N;
    int* deg     = (int*)(ws + off); off += N;
    int* rowptr  = (int*)(ws + off); off += N + 1;
    int* cursor  = (int*)(ws + off); off += N;
    int* bsum    = (int*)(ws + off); off += NB;
    int* csr_snd = (int*)(ws + off); off += E;
    off = (off + 3) & ~(size_t)3;                       // 16B-align for short8 loads
    unsigned short* wq_hi = (unsigned short*)(ws + off); off += (size_t)HOPS * 16384 / 2;

    float* xout_final = (float*)d_out;                  // N*FD
    float* gout = (float*)d_out + (size_t)N * FD;       // G*FD

    // ---- one-time prep: W frags + deg zero (fused), CSR, agg zero (fused)
    const int wtot = HOPS * 2048;
    const int wgrid = (((N > wtot) ? N : wtot) + 255) / 256;
    wprep_kern<<<wgrid, 256, 0, stream>>>(Wq, wq_hi, wtot, deg, N);
    hist_kern<<<(E + 255) / 256, 256, 0, stream>>>(receivers, deg, E);
    scan1_kern<<<NB, 256, 0, stream>>>(deg, rowptr, bsum, N);
    scan2_kern<<<1, 64, 0, stream>>>(bsum, rowptr, NB, N, E);
    scan3_kern<<<(N + 255) / 256, 256, 0, stream>>>(rowptr, cursor, bsum, N,
                                                    agg, G * FD);
    fill_kern<<<(E + 255) / 256, 256, 0, stream>>>(senders, receivers, cursor, csr_snd, E);

    const float* xin = nodes;
    for (int h = 0; h < HOPS; ++h) {
        float* xout = (h == HOPS - 1) ? xout_final : xbuf;
        const unsigned short* whi_h = wq_hi + (size_t)h * 16384;
        const float* bq_h = bq + (size_t)h * FD;
        const float* Wa_h = Wa + (size_t)h * 2 * FD;

        qkern_mfma<<<(N + 127) / 128, 256, 0, stream>>>(xin, whi_h, bq_h,
                                                        Wa_h, q_bfu, as_, N);
        gat_node_kern<<<(N + 7) / 8, 256, 0, stream>>>(q_bfu, as_, rowptr, csr_snd,
                                                       xout, N);
        xin = xout;
    }

    agg_kern<<<(N + 127) / 128, 256, 0, stream>>>(xin, gidx, agg, N);
    glob_kern<<<G, 256, 0, stream>>>(agg, globals_, Wg, bg, gout, G);
}